// Round 1
// baseline (1302.810 us; speedup 1.0000x reference)
//
#include <hip/hip_runtime.h>

#define N_BINS 15
#define BLOCKS 2048

// Layout of d_ws (floats): [0..14]=count, [15..29]=conf_sum, [30..44]=acc_sum
__global__ __launch_bounds__(256) void ece_main(
    const float* __restrict__ probs,
    const int* __restrict__ labels,
    const int* __restrict__ is_logit_p,
    float* __restrict__ bins,
    int n_rows)
{
    __shared__ float s_count[N_BINS];
    __shared__ float s_conf[N_BINS];
    __shared__ float s_acc[N_BINS];

    const int tid = threadIdx.x;
    if (tid < N_BINS) { s_count[tid] = 0.f; s_conf[tid] = 0.f; s_acc[tid] = 0.f; }
    __syncthreads();

    const int is_logit = *is_logit_p;      // wave-uniform scalar load
    const int lane = tid & 63;
    const int wave = tid >> 6;             // 0..3
    const int half = lane >> 5;            // 0 or 1 (two rows per wave)
    const int sub  = lane & 31;            // lane within the 32-lane row group

    const long long row0   = (long long)blockIdx.x * 8 + wave * 2 + half;
    const long long stride = (long long)gridDim.x * 8;

    for (long long row = row0; row < n_rows; row += stride) {
        const float4 v = ((const float4*)(probs + (size_t)row * 128))[sub];

        // ---- max + argmax over the row (first-occurrence tie-break) ----
        float m = v.x; int mi = sub * 4;
        if (v.y > m) { m = v.y; mi = sub * 4 + 1; }
        if (v.z > m) { m = v.z; mi = sub * 4 + 2; }
        if (v.w > m) { m = v.w; mi = sub * 4 + 3; }
        #pragma unroll
        for (int off = 1; off < 32; off <<= 1) {
            float om = __shfl_xor(m, off, 64);
            int   oi = __shfl_xor(mi, off, 64);
            if (om > m || (om == m && oi < mi)) { m = om; mi = oi; }
        }

        // ---- confidence ----
        float conf;
        if (is_logit) {
            float s = __expf(v.x - m) + __expf(v.y - m)
                    + __expf(v.z - m) + __expf(v.w - m);
            #pragma unroll
            for (int off = 1; off < 32; off <<= 1)
                s += __shfl_xor(s, off, 64);
            conf = 1.0f / s;               // max softmax prob = exp(0)/sumexp
        } else {
            conf = m;
        }

        if (sub == 0) {
            int bin = (int)ceilf(conf * (float)N_BINS) - 1;
            bin = bin < 0 ? 0 : (bin > N_BINS - 1 ? N_BINS - 1 : bin);
            float acc = (mi == labels[row]) ? 1.0f : 0.0f;
            atomicAdd(&s_count[bin], 1.0f);
            atomicAdd(&s_conf[bin],  conf);
            atomicAdd(&s_acc[bin],   acc);
        }
    }

    __syncthreads();
    if (tid < N_BINS) {
        atomicAdd(&bins[tid],            s_count[tid]);
        atomicAdd(&bins[N_BINS + tid],   s_conf[tid]);
        atomicAdd(&bins[2*N_BINS + tid], s_acc[tid]);
    }
}

__global__ void ece_final(const float* __restrict__ bins,
                          float* __restrict__ out, int n_rows)
{
    if (threadIdx.x == 0 && blockIdx.x == 0) {
        float ece = 0.f;
        for (int i = 0; i < N_BINS; ++i) {
            float c = bins[i];
            if (c > 0.f) {
                float gap = fabsf(bins[N_BINS + i] / c - bins[2*N_BINS + i] / c);
                ece += gap * (c / (float)n_rows);
            }
        }
        out[0] = ece;
    }
}

extern "C" void kernel_launch(void* const* d_in, const int* in_sizes, int n_in,
                              void* d_out, int out_size, void* d_ws, size_t ws_size,
                              hipStream_t stream) {
    const float* probs    = (const float*)d_in[0];
    const int*   labels   = (const int*)d_in[1];
    const int*   is_logit = (const int*)d_in[2];
    float*       out      = (float*)d_out;
    float*       bins     = (float*)d_ws;
    const int n_rows = in_sizes[1];   // 2,000,000 (labels count == row count)

    hipMemsetAsync(bins, 0, 3 * N_BINS * sizeof(float), stream);
    ece_main<<<BLOCKS, 256, 0, stream>>>(probs, labels, is_logit, bins, n_rows);
    ece_final<<<1, 64, 0, stream>>>(bins, out, n_rows);
}

// Round 2
// 1280.875 us; speedup vs baseline: 1.0171x; 1.0171x over previous
//
#include <hip/hip_runtime.h>

#define N_BINS 15
#define BLOCKS 2048

// d_ws layout (floats): [0..14]=count, [15..29]=conf_sum, [30..44]=acc_sum
__global__ __launch_bounds__(256) void ece_main(
    const float* __restrict__ probs,
    const int* __restrict__ labels,
    const int* __restrict__ is_logit_p,
    float* __restrict__ bins,
    int n_rows)
{
    __shared__ float s_count[N_BINS];
    __shared__ float s_conf[N_BINS];
    __shared__ float s_acc[N_BINS];

    const int tid = threadIdx.x;
    if (tid < N_BINS) { s_count[tid] = 0.f; s_conf[tid] = 0.f; s_acc[tid] = 0.f; }
    __syncthreads();

    const int is_logit = *is_logit_p;   // wave-uniform
    const int lane = tid & 63;
    const int sub  = lane & 7;          // lane within 8-lane row group
    const int grp  = tid >> 3;          // row group within block: 0..31

    long long row = (long long)blockIdx.x * 32 + grp;
    const long long stride = (long long)gridDim.x * 32;

    for (; row < n_rows; row += stride) {
        const float4* rp = (const float4*)(probs + (size_t)row * 128);
        // 16 elements per lane: float4 indices sub, sub+8, sub+16, sub+24
        const float4 v0 = rp[sub];
        const float4 v1 = rp[sub + 8];
        const float4 v2 = rp[sub + 16];
        const float4 v3 = rp[sub + 24];
        const int label = labels[row];

        // ---- local max over 16 elements ----
        float m = fmaxf(fmaxf(fmaxf(v0.x, v0.y), fmaxf(v0.z, v0.w)),
                        fmaxf(fmaxf(v1.x, v1.y), fmaxf(v1.z, v1.w)));
        m = fmaxf(m, fmaxf(fmaxf(fmaxf(v2.x, v2.y), fmaxf(v2.z, v2.w)),
                           fmaxf(fmaxf(v3.x, v3.y), fmaxf(v3.z, v3.w))));
        // ---- group max: 3 xor-shuffles within the 8-lane group ----
        m = fmaxf(m, __shfl_xor(m, 1, 64));
        m = fmaxf(m, __shfl_xor(m, 2, 64));
        m = fmaxf(m, __shfl_xor(m, 4, 64));

        // ---- confidence ----
        float conf;
        if (is_logit) {
            float s = __expf(v0.x - m) + __expf(v0.y - m)
                    + __expf(v0.z - m) + __expf(v0.w - m)
                    + __expf(v1.x - m) + __expf(v1.y - m)
                    + __expf(v1.z - m) + __expf(v1.w - m)
                    + __expf(v2.x - m) + __expf(v2.y - m)
                    + __expf(v2.z - m) + __expf(v2.w - m)
                    + __expf(v3.x - m) + __expf(v3.y - m)
                    + __expf(v3.z - m) + __expf(v3.w - m);
            s += __shfl_xor(s, 1, 64);
            s += __shfl_xor(s, 2, 64);
            s += __shfl_xor(s, 4, 64);
            conf = 1.0f / s;            // max softmax prob = 1 / sum(exp(x-m))
        } else {
            conf = m;
        }

        // ---- accuracy: does the label position hold the row max? ----
        const int f = label >> 2;       // float4 index of label
        const int c = label & 3;        // component
        const int k = f >> 3;           // which of v0..v3
        float4 vk = (k == 0) ? v0 : (k == 1) ? v1 : (k == 2) ? v2 : v3;
        float lv = (c == 0) ? vk.x : (c == 1) ? vk.y : (c == 2) ? vk.z : vk.w;
        const bool mine = ((f & 7) == sub) && (lv == m);
        const unsigned long long bal = __ballot(mine);

        if (sub == 0) {
            int bin = (int)ceilf(conf * (float)N_BINS) - 1;
            bin = bin < 0 ? 0 : (bin > N_BINS - 1 ? N_BINS - 1 : bin);
            const float acc = ((bal >> (lane & 56)) & 0xFFull) ? 1.0f : 0.0f;
            atomicAdd(&s_count[bin], 1.0f);
            atomicAdd(&s_conf[bin],  conf);
            atomicAdd(&s_acc[bin],   acc);
        }
    }

    __syncthreads();
    if (tid < N_BINS) {
        atomicAdd(&bins[tid],            s_count[tid]);
        atomicAdd(&bins[N_BINS + tid],   s_conf[tid]);
        atomicAdd(&bins[2*N_BINS + tid], s_acc[tid]);
    }
}

__global__ void ece_final(const float* __restrict__ bins,
                          float* __restrict__ out, int n_rows)
{
    if (threadIdx.x == 0 && blockIdx.x == 0) {
        float ece = 0.f;
        for (int i = 0; i < N_BINS; ++i) {
            float c = bins[i];
            if (c > 0.f) {
                float gap = fabsf(bins[N_BINS + i] / c - bins[2*N_BINS + i] / c);
                ece += gap * (c / (float)n_rows);
            }
        }
        out[0] = ece;
    }
}

extern "C" void kernel_launch(void* const* d_in, const int* in_sizes, int n_in,
                              void* d_out, int out_size, void* d_ws, size_t ws_size,
                              hipStream_t stream) {
    const float* probs    = (const float*)d_in[0];
    const int*   labels   = (const int*)d_in[1];
    const int*   is_logit = (const int*)d_in[2];
    float*       out      = (float*)d_out;
    float*       bins     = (float*)d_ws;
    const int n_rows = in_sizes[1];   // 2,000,000

    hipMemsetAsync(bins, 0, 3 * N_BINS * sizeof(float), stream);
    ece_main<<<BLOCKS, 256, 0, stream>>>(probs, labels, is_logit, bins, n_rows);
    ece_final<<<1, 64, 0, stream>>>(bins, out, n_rows);
}